// Round 9
// baseline (571.014 us; speedup 1.0000x reference)
//
#include <hip/hip_runtime.h>
#include <hip/hip_bf16.h>

typedef __bf16 bf16x8 __attribute__((ext_vector_type(8)));
typedef float f32x4 __attribute__((ext_vector_type(4)));

#define N_NODES 50000
#define NEDGE 160000
#define NSLOT (2 * N_NODES)
#define NB 3125              // buckets of 32 slots: 3125 * 32 = 100000
#define SCAN_N 25600         // NB*8 = 25000 sub-segments, padded to 25*1024
#define SBLKS 25
#define HSZ ((size_t)N_NODES * 128)

// ---- workspace layout (bytes) ----
constexpr size_t OFF_WFRAG = 0;                                    // 65536
constexpr size_t OFF_XB    = 65536;                                // 25.6 MB
constexpr size_t OFF_Y     = OFF_XB + 25600000;                    // 51.2 MB
constexpr size_t OFF_CNT   = OFF_Y + 51200000;                     // SCAN_N*4
constexpr size_t OFF_IPTR  = OFF_CNT + (size_t)SCAN_N * 4;         // SCAN_N*4
constexpr size_t OFF_CUR   = OFF_IPTR + (size_t)SCAN_N * 4;        // SCAN_N*4
constexpr size_t OFF_PART  = OFF_CUR + (size_t)SCAN_N * 4;         // pad 1024
constexpr size_t OFF_EBUF  = OFF_PART + 1024;                      // 4E*4 = 2.56 MB

// Basis fragments: offset = (((b*8+n)*4+kk)*64+lane)*8 + j
// element = weight[b][k][o], k = kk*32 + (lane>>4)*8 + j, o = n*16 + (lane&15)
__global__ __launch_bounds__(256) void wfrag_kernel(const float* __restrict__ weight,
                                                    __bf16* __restrict__ wfrag) {
    int tid = blockIdx.x * 256 + threadIdx.x;  // 32768 total
    int j    = tid & 7;
    int lane = (tid >> 3) & 63;
    int kk   = (tid >> 9) & 3;
    int n    = (tid >> 11) & 7;
    int b    = tid >> 14;
    int k = kk * 32 + ((lane >> 4) << 3) + j;
    int o = (n << 4) + (lane & 15);
    wfrag[tid] = (__bf16)weight[b * 16384 + k * 128 + o];
}

// xb[type*N + row] = bf16(x_type[row]), 8 floats -> 8 bf16 per thread
__global__ __launch_bounds__(256) void cast_kernel(const float* __restrict__ x0,
                                                   const float* __restrict__ x1,
                                                   __bf16* __restrict__ xb) {
    int ty = blockIdx.y;
    const float* x = ty ? x1 : x0;
    __bf16* o = xb + (size_t)ty * HSZ;
    int i = blockIdx.x * 256 + threadIdx.x;
    float4 f0 = reinterpret_cast<const float4*>(x)[2 * i];
    float4 f1 = reinterpret_cast<const float4*>(x)[2 * i + 1];
    union { __bf16 b[8]; uint4 v; } pk;
    pk.b[0] = (__bf16)f0.x; pk.b[1] = (__bf16)f0.y;
    pk.b[2] = (__bf16)f0.z; pk.b[3] = (__bf16)f0.w;
    pk.b[4] = (__bf16)f1.x; pk.b[5] = (__bf16)f1.y;
    pk.b[6] = (__bf16)f1.z; pk.b[7] = (__bf16)f1.w;
    reinterpret_cast<uint4*>(o)[i] = pk.v;
}

// counts[bucket*8 + (blockIdx&7)] += 1 per edge; slot = dst_ntype*N + dst.
__global__ __launch_bounds__(256) void bucket_hist_kernel(const int* __restrict__ d0,
                                                          const int* __restrict__ d1,
                                                          const int* __restrict__ d2,
                                                          const int* __restrict__ d3,
                                                          int* __restrict__ counts) {
    int tid = blockIdx.x * 256 + threadIdx.x;
    if (tid >= NEDGE) return;
    int sub = blockIdx.x & 7;
    int s0 = d0[tid];
    int s1 = N_NODES + d1[tid];
    int s2 = d2[tid];
    int s3 = N_NODES + d3[tid];
    atomicAdd(&counts[(s0 >> 5) * 8 + sub], 1);
    atomicAdd(&counts[(s1 >> 5) * 8 + sub], 1);
    atomicAdd(&counts[(s2 >> 5) * 8 + sub], 1);
    atomicAdd(&counts[(s3 >> 5) * 8 + sub], 1);
}

// Per-block partial sums: 25 blocks x 1024 counts (int4 per thread).
__global__ __launch_bounds__(256) void block_sums_kernel(const int* __restrict__ counts,
                                                         int* __restrict__ partials) {
    int4 v = (reinterpret_cast<const int4*>(counts) + blockIdx.x * 256)[threadIdx.x];
    int s = v.x + v.y + v.z + v.w;
#pragma unroll
    for (int d = 1; d < 64; d <<= 1) s += __shfl_xor(s, d, 64);
    __shared__ int wsum[4];
    int wave = threadIdx.x >> 6;
    int lane = threadIdx.x & 63;
    if (lane == 0) wsum[wave] = s;
    __syncthreads();
    if (threadIdx.x == 0)
        partials[blockIdx.x] = wsum[0] + wsum[1] + wsum[2] + wsum[3];
}

// Exclusive scan -> ebase (indptr) and cursor (int4 stores).
__global__ __launch_bounds__(256) void scan_write_kernel(const int* __restrict__ counts,
                                                         const int* __restrict__ partials,
                                                         int* __restrict__ ebase,
                                                         int* __restrict__ cursor) {
    int blk = blockIdx.x;
    int lane = threadIdx.x & 63;
    int wave = threadIdx.x >> 6;

    int pv = (lane < blk) ? partials[lane] : 0;   // blk <= 24 < 64
#pragma unroll
    for (int d = 1; d < 64; d <<= 1) pv += __shfl_xor(pv, d, 64);

    int4 v = (reinterpret_cast<const int4*>(counts) + blk * 256)[threadIdx.x];
    int ts = v.x + v.y + v.z + v.w;

    int s = ts;
#pragma unroll
    for (int d = 1; d < 64; d <<= 1) {
        int n = __shfl_up(s, d, 64);
        if (lane >= d) s += n;
    }
    int exclw = s - ts;

    __shared__ int wtot[4];
    if (lane == 63) wtot[wave] = s;
    __syncthreads();
    int woff = 0;
    if (wave > 0) woff += wtot[0];
    if (wave > 1) woff += wtot[1];
    if (wave > 2) woff += wtot[2];

    int e0 = pv + woff + exclw;
    int4 ip;
    ip.x = e0;
    ip.y = e0 + v.x;
    ip.z = ip.y + v.y;
    ip.w = ip.z + v.z;
    reinterpret_cast<int4*>(ebase)[blk * 256 + threadIdx.x] = ip;
    reinterpret_cast<int4*>(cursor)[blk * 256 + threadIdx.x] = ip;
}

// Append packed edge u32 = src16 | local5<<16 | isB<<21 to its sub-segment.
// blockIdx&7 sub-bucketing keeps each sub-segment's lines XCD-local -> L2 merge.
__global__ __launch_bounds__(256) void bucket_fill_kernel(const int* __restrict__ s0, const int* __restrict__ d0,
                                                          const int* __restrict__ s1, const int* __restrict__ d1,
                                                          const int* __restrict__ s2, const int* __restrict__ d2,
                                                          const int* __restrict__ s3, const int* __restrict__ d3,
                                                          int* __restrict__ cursor,
                                                          unsigned int* __restrict__ ebuf) {
    int tid = blockIdx.x * 256 + threadIdx.x;
    if (tid >= NEDGE) return;
    int sub = blockIdx.x & 7;
    {
        int slot = d0[tid];
        int pos = atomicAdd(&cursor[(slot >> 5) * 8 + sub], 1);
        ebuf[pos] = (unsigned)s0[tid] | ((unsigned)(slot & 31) << 16);
    }
    {
        int slot = N_NODES + d1[tid];
        int pos = atomicAdd(&cursor[(slot >> 5) * 8 + sub], 1);
        ebuf[pos] = (unsigned)s1[tid] | ((unsigned)(slot & 31) << 16);
    }
    {
        int slot = d2[tid];
        int pos = atomicAdd(&cursor[(slot >> 5) * 8 + sub], 1);
        ebuf[pos] = (unsigned)s2[tid] | ((unsigned)(slot & 31) << 16) | (1u << 21);
    }
    {
        int slot = N_NODES + d3[tid];
        int pos = atomicAdd(&cursor[(slot >> 5) * 8 + sub], 1);
        ebuf[pos] = (unsigned)s3[tid] | ((unsigned)(slot & 31) << 16) | (1u << 21);
    }
}

// One block per bucket (32 slots). Gather xb rows for the bucket's edges,
// accumulate into LDS f32 tile via ds atomics (8-edge MLP unroll), then apply
// w_comp coefficients and write y (bf16, nontemporal).
// LDS layout: acc[slot][isB][half*64 + lane] holds feat 2*lane+half.
__global__ __launch_bounds__(256) void aggregate_fused_kernel(const __bf16* __restrict__ xb,
                                                              const int* __restrict__ ebase,
                                                              const unsigned int* __restrict__ ebuf,
                                                              const float* __restrict__ wcomp,
                                                              __bf16* __restrict__ y) {
    __shared__ float acc[32 * 256];   // 32 KB
    {
        float4* az = reinterpret_cast<float4*>(acc);
#pragma unroll
        for (int i = 0; i < 8; ++i)
            az[threadIdx.x + 256 * i] = (float4){0.f, 0.f, 0.f, 0.f};
    }
    __syncthreads();

    int b = blockIdx.x;
    int e0 = ebase[b * 8];
    int n = ebase[(b + 1) * 8] - e0;
    const unsigned int* ep = ebuf + e0;
    int lane = threadIdx.x & 63;
    int wave = threadIdx.x >> 6;
    const unsigned int* xbu = reinterpret_cast<const unsigned int*>(xb);

    for (int base = wave * 8; base < n; base += 32) {
        unsigned int ew[8], hv[8];
#pragma unroll
        for (int u = 0; u < 8; ++u) {
            int j = base + u;
            ew[u] = ep[j < n ? j : n - 1];
        }
#pragma unroll
        for (int u = 0; u < 8; ++u) {
            unsigned int w = ew[u];
            unsigned int idx = (w & 0xffffu) * 64u + ((w >> 21) & 1u) * 3200000u + lane;
            unsigned int v = xbu[idx];
            hv[u] = (base + u < n) ? v : 0u;   // tail adds 0.0
        }
#pragma unroll
        for (int u = 0; u < 8; ++u) {
            unsigned int w = ew[u];
            int t = (((w >> 16) & 31u) << 8) | (((w >> 21) & 1u) << 7) | lane;
            union { unsigned int u32; float f; } lo, hi;
            lo.u32 = hv[u] << 16;
            hi.u32 = hv[u] & 0xFFFF0000u;
            atomicAdd(&acc[t], lo.f);
            atomicAdd(&acc[t + 64], hi.f);
        }
    }
    __syncthreads();

    // write-out: 4096 u32 outputs = 32 slots x 2 bases x 64 feat-pairs
    float cc[8];
#pragma unroll
    for (int i = 0; i < 8; ++i) cc[i] = wcomp[i];
    unsigned int* yu = reinterpret_cast<unsigned int*>(y);
#pragma unroll
    for (int i = 0; i < 16; ++i) {
        int o = threadIdx.x + 256 * i;
        int sl = o >> 7;
        int rem = o & 127;
        int basis = rem >> 6;
        int k = rem & 63;
        int slot = b * 32 + sl;
        int p = slot >= N_NODES;
        float cA = cc[p * 2 + basis];
        float cB = cc[(p + 2) * 2 + basis];
        float f0 = cA * acc[(sl << 8) + k] + cB * acc[(sl << 8) + 128 + k];
        float f1 = cA * acc[(sl << 8) + 64 + k] + cB * acc[(sl << 8) + 192 + k];
        union { __bf16 bb[2]; unsigned int u; } pk;
        pk.bb[0] = (__bf16)f0;
        pk.bb[1] = (__bf16)f1;
        __builtin_nontemporal_store(pk.u, &yu[(size_t)slot * 128 + basis * 64 + k]);
    }
}

// out[slot] = y[slot][0]*B0 + y[slot][1]*B1 + bias. Operand-swapped MFMA
// (basis W^T as A) -> float4 stores. 64 slots/block, basis frags in LDS.
__global__ __launch_bounds__(256) void gemm_out_kernel(const __bf16* __restrict__ y,
                                                       const __bf16* __restrict__ wfrag,
                                                       const float* __restrict__ bias,
                                                       float* __restrict__ out) {
    __shared__ __bf16 wl[32768];  // 64 KB: both basis frag sets
    {
        const uint4* s = reinterpret_cast<const uint4*>(wfrag);
        uint4* dst = reinterpret_cast<uint4*>(wl);
        int t = threadIdx.x;
#pragma unroll
        for (int i = 0; i < 16; ++i) dst[t + i * 256] = s[t + i * 256];
    }
    __syncthreads();

    const int lane = threadIdx.x & 63;
    const int wave = threadIdx.x >> 6;
    const int g = lane >> 4;
    const int m15 = lane & 15;

    int node = blockIdx.x * 64 + wave * 16 + m15;
    int nodec = node < NSLOT ? node : NSLOT - 1;
    const __bf16* yr = y + (size_t)nodec * 256 + g * 8;

    bf16x8 yfrag[2][4];
#pragma unroll
    for (int b = 0; b < 2; ++b)
#pragma unroll
        for (int kk = 0; kk < 4; ++kk)
            yfrag[b][kk] = *reinterpret_cast<const bf16x8*>(yr + b * 128 + kk * 32);

    const bf16x8* wv = reinterpret_cast<const bf16x8*>(wl);
    bool valid = node < NSLOT;
    float* orow = out + (size_t)node * 128;

#pragma unroll
    for (int n = 0; n < 8; ++n) {
        float4 bv = *reinterpret_cast<const float4*>(bias + n * 16 + g * 4);
        f32x4 acc = (f32x4){bv.x, bv.y, bv.z, bv.w};
#pragma unroll
        for (int b = 0; b < 2; ++b)
#pragma unroll
            for (int kk = 0; kk < 4; ++kk)
                acc = __builtin_amdgcn_mfma_f32_16x16x32_bf16(
                    wv[((b * 8 + n) * 4 + kk) * 64 + lane], yfrag[b][kk], acc, 0, 0, 0);
        if (valid)
            *reinterpret_cast<float4*>(orow + n * 16 + g * 4) =
                (float4){acc[0], acc[1], acc[2], acc[3]};
    }
}

extern "C" void kernel_launch(void* const* d_in, const int* in_sizes, int n_in,
                              void* d_out, int out_size, void* d_ws, size_t ws_size,
                              hipStream_t stream) {
    const float* x0     = (const float*)d_in[0];
    const float* x1     = (const float*)d_in[1];
    const float* weight = (const float*)d_in[2];
    const float* wcomp  = (const float*)d_in[3];
    const float* bias   = (const float*)d_in[4];
    const int* src[4] = {(const int*)d_in[5], (const int*)d_in[7],
                         (const int*)d_in[9], (const int*)d_in[11]};
    const int* dst[4] = {(const int*)d_in[6], (const int*)d_in[8],
                         (const int*)d_in[10], (const int*)d_in[12]};
    float* out = (float*)d_out;

    char* ws = (char*)d_ws;
    __bf16* wfrag = (__bf16*)(ws + OFF_WFRAG);
    __bf16* xb    = (__bf16*)(ws + OFF_XB);
    __bf16* y     = (__bf16*)(ws + OFF_Y);
    int* counts   = (int*)(ws + OFF_CNT);
    int* ebase    = (int*)(ws + OFF_IPTR);
    int* cursor   = (int*)(ws + OFF_CUR);
    int* partials = (int*)(ws + OFF_PART);
    unsigned int* ebuf = (unsigned int*)(ws + OFF_EBUF);

    wfrag_kernel<<<128, 256, 0, stream>>>(weight, wfrag);
    cast_kernel<<<dim3(3125, 2), 256, 0, stream>>>(x0, x1, xb);

    // ---- bucketed edge grouping (XCD-local sub-segments) ----
    hipMemsetAsync(counts, 0, (size_t)SCAN_N * 4, stream);
    bucket_hist_kernel<<<(NEDGE + 255) / 256, 256, 0, stream>>>(
        dst[0], dst[1], dst[2], dst[3], counts);
    block_sums_kernel<<<SBLKS, 256, 0, stream>>>(counts, partials);
    scan_write_kernel<<<SBLKS, 256, 0, stream>>>(counts, partials, ebase, cursor);
    bucket_fill_kernel<<<(NEDGE + 255) / 256, 256, 0, stream>>>(
        src[0], dst[0], src[1], dst[1], src[2], dst[2], src[3], dst[3],
        cursor, ebuf);

    // ---- fused gather + LDS accumulate + coefficient combine -> y ----
    aggregate_fused_kernel<<<NB, 256, 0, stream>>>(xb, ebase, ebuf, wcomp, y);

    // ---- dense epilogue: out = y0*B0 + y1*B1 + bias ----
    gemm_out_kernel<<<(NSLOT + 63) / 64, 256, 0, stream>>>(y, wfrag, bias, out);
}

// Round 10
// 140.829 us; speedup vs baseline: 4.0547x; 4.0547x over previous
//
#include <hip/hip_runtime.h>
#include <hip/hip_bf16.h>

typedef __bf16 bf16x8 __attribute__((ext_vector_type(8)));
typedef float f32x4 __attribute__((ext_vector_type(4)));

#define N_NODES 50000
#define NEDGE 160000
#define NSLOT (2 * N_NODES)
#define NB 3125              // buckets of 32 slots: 3125 * 32 = 100000
#define CAPS 96              // capacity per (bucket, sub) segment
#define SCAP 768             // 8 * CAPS, per-bucket srcids capacity
#define HSZ ((size_t)N_NODES * 128)

// ---- workspace layout (bytes) ----
constexpr size_t OFF_WFRAG = 0;                                   // 4 rel frag sets, 131072
constexpr size_t OFF_H     = 131072;                              // 4 * 12.8 MB
constexpr size_t OFF_CNT   = OFF_H + 4 * 12800000;                // 25000*4, pad
constexpr size_t OFF_SBEG  = OFF_CNT + 102400;                    // 100000*4, pad
constexpr size_t OFF_SCNT  = OFF_SBEG + 401408;                   // 100000*4, pad
constexpr size_t OFF_EBUF  = OFF_SCNT + 401408;                   // 25000*96*4 = 9.6 MB
constexpr size_t OFF_SRC   = OFF_EBUF + 9600000;                  // 3125*768*2 = 4.8 MB

// Compose W[r] = w_comp[r,0]*weight[0] + w_comp[r,1]*weight[1], store bf16 in
// MFMA B-fragment order: offset = (((r*8+n)*4+kk)*64+lane)*8 + j
// element = W[r][k][o], k = kk*32 + (lane>>4)*8 + j, o = n*16 + (lane&15)
__global__ __launch_bounds__(256) void wfrag_kernel(const float* __restrict__ weight,
                                                    const float* __restrict__ wcomp,
                                                    __bf16* __restrict__ wfrag) {
    int tid = blockIdx.x * 256 + threadIdx.x;  // 65536 total
    int j    = tid & 7;
    int lane = (tid >> 3) & 63;
    int kk   = (tid >> 9) & 3;
    int n    = (tid >> 11) & 7;
    int r    = tid >> 14;
    int k = kk * 32 + ((lane >> 4) << 3) + j;
    int o = (n << 4) + (lane & 15);
    float v = wcomp[r * 2] * weight[k * 128 + o] +
              wcomp[r * 2 + 1] * weight[16384 + k * 128 + o];
    wfrag[tid] = (__bf16)v;
}

// H[2y+rr] = x_y @ W_{2y+rr} for rr in {0,1}. A-fragments loaded once per block.
__global__ __launch_bounds__(256) void gemm2_kernel(const float* __restrict__ x0,
                                                    const float* __restrict__ x1,
                                                    const __bf16* __restrict__ wfrag,
                                                    __bf16* __restrict__ Hbase, int M) {
    __shared__ __bf16 wl[16384];  // 32 KB: [n][kk][lane][8]
    const int y = blockIdx.y;     // src ntype
    const float* x = y ? x1 : x0;

    const int lane = threadIdx.x & 63;
    const int wave = threadIdx.x >> 6;
    const int g = lane >> 4;
    const int m15 = lane & 15;

    int row = blockIdx.x * 64 + wave * 16 + m15;
    int rowc = row < M ? row : M - 1;
    const float* xr = x + (size_t)rowc * 128 + g * 8;

    bf16x8 a[4];
#pragma unroll
    for (int kk = 0; kk < 4; ++kk) {
        float4 f0 = *reinterpret_cast<const float4*>(xr + kk * 32);
        float4 f1 = *reinterpret_cast<const float4*>(xr + kk * 32 + 4);
        bf16x8 t;
        t[0] = (__bf16)f0.x; t[1] = (__bf16)f0.y; t[2] = (__bf16)f0.z; t[3] = (__bf16)f0.w;
        t[4] = (__bf16)f1.x; t[5] = (__bf16)f1.y; t[6] = (__bf16)f1.z; t[7] = (__bf16)f1.w;
        a[kk] = t;
    }

    const bf16x8* wv = reinterpret_cast<const bf16x8*>(wl);
    int rowbase = blockIdx.x * 64 + wave * 16 + g * 4;

#pragma unroll
    for (int rr = 0; rr < 2; ++rr) {
        int rel = 2 * y + rr;
        if (rr) __syncthreads();  // previous compute done reading wl
        {
            const uint4* s = reinterpret_cast<const uint4*>(wfrag + rel * 16384);
            uint4* dsl = reinterpret_cast<uint4*>(wl);
            int t = threadIdx.x;
#pragma unroll
            for (int i = 0; i < 8; ++i) dsl[t + i * 256] = s[t + i * 256];
        }
        __syncthreads();

        f32x4 acc[8];
#pragma unroll
        for (int n = 0; n < 8; ++n) acc[n] = (f32x4){0.f, 0.f, 0.f, 0.f};
#pragma unroll
        for (int n = 0; n < 8; ++n) {
#pragma unroll
            for (int kk = 0; kk < 4; ++kk) {
                acc[n] = __builtin_amdgcn_mfma_f32_16x16x32_bf16(
                    a[kk], wv[(n * 4 + kk) * 64 + lane], acc[n], 0, 0, 0);
            }
        }

        __bf16* H = Hbase + (size_t)rel * HSZ;
#pragma unroll
        for (int n = 0; n < 8; ++n) {
#pragma unroll
            for (int q = 0; q < 4; ++q) {
                int rrow = rowbase + q;
                if (rrow < M) H[(size_t)rrow * 128 + n * 16 + m15] = (__bf16)acc[n][q];
            }
        }
    }
}

// Append packed edge u32 = src16 | local5<<16 | isB<<21 into fixed-capacity
// (bucket, blockIdx&7) segment. slot = dst_ntype*N + dst; bucket = slot>>5.
// Sub-bucketing by blockIdx&7 keeps each segment's lines XCD-local.
__global__ __launch_bounds__(256) void bucket_fill_kernel(const int* __restrict__ s0, const int* __restrict__ d0,
                                                          const int* __restrict__ s1, const int* __restrict__ d1,
                                                          const int* __restrict__ s2, const int* __restrict__ d2,
                                                          const int* __restrict__ s3, const int* __restrict__ d3,
                                                          int* __restrict__ cnt,
                                                          unsigned int* __restrict__ ebuf) {
    int tid = blockIdx.x * 256 + threadIdx.x;
    if (tid >= NEDGE) return;
    int sub = blockIdx.x & 7;
    {
        int slot = d0[tid];
        int seg = (slot >> 5) * 8 + sub;
        int pos = atomicAdd(&cnt[seg], 1);
        if (pos < CAPS) ebuf[seg * CAPS + pos] = (unsigned)s0[tid] | ((unsigned)(slot & 31) << 16);
    }
    {
        int slot = N_NODES + d1[tid];
        int seg = (slot >> 5) * 8 + sub;
        int pos = atomicAdd(&cnt[seg], 1);
        if (pos < CAPS) ebuf[seg * CAPS + pos] = (unsigned)s1[tid] | ((unsigned)(slot & 31) << 16);
    }
    {
        int slot = d2[tid];
        int seg = (slot >> 5) * 8 + sub;
        int pos = atomicAdd(&cnt[seg], 1);
        if (pos < CAPS) ebuf[seg * CAPS + pos] = (unsigned)s2[tid] | ((unsigned)(slot & 31) << 16) | (1u << 21);
    }
    {
        int slot = N_NODES + d3[tid];
        int seg = (slot >> 5) * 8 + sub;
        int pos = atomicAdd(&cnt[seg], 1);
        if (pos < CAPS) ebuf[seg * CAPS + pos] = (unsigned)s3[tid] | ((unsigned)(slot & 31) << 16) | (1u << 21);
    }
}

// One block per bucket: LDS counting-sort of the bucket's edges by key
// (localslot*2 + isB), write coalesced uint16 srcids + per-slot (dA, dB).
__global__ __launch_bounds__(256) void bucket_sort_kernel(const unsigned int* __restrict__ ebuf,
                                                          const int* __restrict__ cnt,
                                                          unsigned short* __restrict__ srcids,
                                                          int* __restrict__ sbeg,
                                                          unsigned int* __restrict__ scnt) {
    __shared__ alignas(16) unsigned short sbuf[SCAP];
    __shared__ int lcnt[64];
    __shared__ int lex[64];
    __shared__ int lcur[64];
    int b = blockIdx.x;
    int t = threadIdx.x;
    if (t < 64) lcnt[t] = 0;
    __syncthreads();

    int cs[8];
#pragma unroll
    for (int s = 0; s < 8; ++s) {
        int c = cnt[b * 8 + s];
        cs[s] = c < CAPS ? c : CAPS;
    }
#pragma unroll
    for (int s = 0; s < 8; ++s)
        for (int j = t; j < cs[s]; j += 256) {
            unsigned int w = ebuf[(b * 8 + s) * CAPS + j];
            int key = ((w >> 15) & 62) | ((w >> 21) & 1);
            atomicAdd(&lcnt[key], 1);
        }
    __syncthreads();

    if (t < 64) {  // wave 0: exclusive scan of 64 keys
        int v = lcnt[t];
        int s = v;
#pragma unroll
        for (int dd = 1; dd < 64; dd <<= 1) {
            int n = __shfl_up(s, dd, 64);
            if (t >= dd) s += n;
        }
        lex[t] = s - v;
        lcur[t] = s - v;
    }
    __syncthreads();

#pragma unroll
    for (int s = 0; s < 8; ++s)
        for (int j = t; j < cs[s]; j += 256) {
            unsigned int w = ebuf[(b * 8 + s) * CAPS + j];
            int key = ((w >> 15) & 62) | ((w >> 21) & 1);
            int pos = atomicAdd(&lcur[key], 1);
            sbuf[pos] = (unsigned short)(w & 0xffffu);
        }
    __syncthreads();

    int n = lex[63] + lcnt[63];
    unsigned int* du = reinterpret_cast<unsigned int*>(srcids + (size_t)b * SCAP);
    const unsigned int* su = reinterpret_cast<const unsigned int*>(sbuf);
    for (int j = t; 2 * j < n; j += 256) du[j] = su[j];
    if (t < 32) {
        int slot = b * 32 + t;
        sbeg[slot] = b * SCAP + lex[t * 2];
        scnt[slot] = (unsigned)lcnt[t * 2] | ((unsigned)lcnt[t * 2 + 1] << 16);
    }
}

// One wave per dst slot: out[slot] = bias + sum_A H[p][src] + sum_B H[p+2][src].
// Virtual-concat walk of [A-seg][B-seg] with 4-way MLP unroll (R4-proven shape).
__global__ __launch_bounds__(256) void aggregate_all_kernel(const __bf16* __restrict__ Hbase,
                                                            const int* __restrict__ sbeg,
                                                            const unsigned int* __restrict__ scnt,
                                                            const unsigned short* __restrict__ srcids,
                                                            const float* __restrict__ bias,
                                                            float* __restrict__ out) {
    int idx = blockIdx.x * 256 + threadIdx.x;
    int slot = idx >> 6;
    int lane = idx & 63;
    int p = slot >= N_NODES;

    int beg = sbeg[slot];
    unsigned int c = scnt[slot];
    int dA = (int)(c & 0xffffu);
    int d = dA + (int)(c >> 16);
    const unsigned short* sp = srcids + beg;

    const unsigned int* HA = reinterpret_cast<const unsigned int*>(Hbase + (size_t)p * HSZ);
    const unsigned int* HB = reinterpret_cast<const unsigned int*>(Hbase + (size_t)(p + 2) * HSZ);

    float2 bv = *reinterpret_cast<const float2*>(bias + 2 * lane);
    float acc0 = bv.x, acc1 = bv.y;

    for (int i = 0; i < d; i += 4) {
        unsigned int hv[4];
#pragma unroll
        for (int k = 0; k < 4; ++k) {
            int j = i + k;
            int jc = j < d ? j : d - 1;     // clamp -> L1-hit re-read
            unsigned int s = sp[jc];
            const unsigned int* Hp = (jc >= dA) ? HB : HA;
            unsigned int v = Hp[(size_t)s * 64 + lane];
            hv[k] = (j < d) ? v : 0u;
        }
#pragma unroll
        for (int k = 0; k < 4; ++k) {
            union { unsigned int u; float f; } lo, hi;
            lo.u = hv[k] << 16;
            hi.u = hv[k] & 0xFFFF0000u;
            acc0 += lo.f;
            acc1 += hi.f;
        }
    }
    *reinterpret_cast<float2*>(out + (size_t)slot * 128 + 2 * lane) =
        make_float2(acc0, acc1);
}

extern "C" void kernel_launch(void* const* d_in, const int* in_sizes, int n_in,
                              void* d_out, int out_size, void* d_ws, size_t ws_size,
                              hipStream_t stream) {
    const float* x0     = (const float*)d_in[0];
    const float* x1     = (const float*)d_in[1];
    const float* weight = (const float*)d_in[2];
    const float* wcomp  = (const float*)d_in[3];
    const float* bias   = (const float*)d_in[4];
    const int* src[4] = {(const int*)d_in[5], (const int*)d_in[7],
                         (const int*)d_in[9], (const int*)d_in[11]};
    const int* dst[4] = {(const int*)d_in[6], (const int*)d_in[8],
                         (const int*)d_in[10], (const int*)d_in[12]};
    float* out = (float*)d_out;

    char* ws = (char*)d_ws;
    __bf16* wfrag = (__bf16*)(ws + OFF_WFRAG);
    __bf16* Hbase = (__bf16*)(ws + OFF_H);
    int* cnt      = (int*)(ws + OFF_CNT);
    int* sbeg     = (int*)(ws + OFF_SBEG);
    unsigned int* scnt = (unsigned int*)(ws + OFF_SCNT);
    unsigned int* ebuf = (unsigned int*)(ws + OFF_EBUF);
    unsigned short* srcids = (unsigned short*)(ws + OFF_SRC);

    wfrag_kernel<<<256, 256, 0, stream>>>(weight, wcomp, wfrag);

    // ---- bucketed CSR build: fixed-capacity fill + per-bucket LDS sort ----
    hipMemsetAsync(cnt, 0, (size_t)NB * 8 * 4, stream);
    bucket_fill_kernel<<<(NEDGE + 255) / 256, 256, 0, stream>>>(
        src[0], dst[0], src[1], dst[1], src[2], dst[2], src[3], dst[3],
        cnt, ebuf);
    bucket_sort_kernel<<<NB, 256, 0, stream>>>(ebuf, cnt, srcids, sbeg, scnt);

    // ---- all 4 GEMMs in one dispatch ----
    gemm2_kernel<<<dim3((N_NODES + 63) / 64, 2), 256, 0, stream>>>(
        x0, x1, wfrag, Hbase, N_NODES);

    // ---- fused aggregation over both dst ntypes ----
    aggregate_all_kernel<<<NSLOT * 64 / 256, 256, 0, stream>>>(
        Hbase, sbeg, scnt, srcids, bias, out);
}